// Round 2
// baseline (561.965 us; speedup 1.0000x reference)
//
#include <hip/hip_runtime.h>
#include <math.h>

// Last-write-wins scatter without touching the big output matrix 3x:
//   slot key = src*8192+dst fits in 26 bits -> 32-bit keys.
//   Open-addressing hash table (2^21 entries, 16 MB, LLC-resident):
//     keys[h] claimed via atomicCAS (stored as key+1, 0 = empty)
//     vals[h] = max(pair_id+1) via atomicMax  -> last pair in order wins.
//   Then one pass: probe, winner computes dot and writes output slot.

#define TS_LOG 21
#define TS (1u << TS_LOG)
#define TMASK (TS - 1u)

__device__ __forceinline__ unsigned hash_key(unsigned key) {
    return (key * 2654435761u) >> (32 - TS_LOG);
}

__global__ void k_insert(const int* __restrict__ src, const int* __restrict__ dst,
                         unsigned* __restrict__ keys, unsigned* __restrict__ vals,
                         int P, unsigned N) {
    int p = blockIdx.x * blockDim.x + threadIdx.x;
    if (p >= P) return;
    unsigned key = (unsigned)src[p] * N + (unsigned)dst[p];
    unsigned sk = key + 1u;
    unsigned h = hash_key(key) & TMASK;
    for (;;) {
        unsigned k = keys[h];
        if (k == 0u) {
            unsigned old = atomicCAS(&keys[h], 0u, sk);
            if (old == 0u || old == sk) break;
            k = old;
        }
        if (k == sk) break;
        h = (h + 1u) & TMASK;
    }
    atomicMax(&vals[h], (unsigned)(p + 1));
}

__global__ void k_compute(const float4* __restrict__ ea, const int4* __restrict__ paths,
                          const float4* __restrict__ ev, const int* __restrict__ src,
                          const int* __restrict__ dst, const unsigned* __restrict__ keys,
                          const unsigned* __restrict__ vals, float* __restrict__ out,
                          int P, unsigned N) {
    __shared__ float4 sev[32];            // edge_vector: 8 x 16 fp32 = 32 float4
    int t = threadIdx.x;
    if (t < 32) sev[t] = ev[t];
    __syncthreads();
    int p = blockIdx.x * blockDim.x + t;
    if (p >= P) return;

    unsigned key = (unsigned)src[p] * N + (unsigned)dst[p];
    unsigned sk = key + 1u;
    unsigned h = hash_key(key) & TMASK;
    while (keys[h] != sk) h = (h + 1u) & TMASK;   // table finalized: read-only probe
    if (vals[h] != (unsigned)(p + 1)) return;     // not the last writer for this slot

    int4 i0 = paths[(size_t)p * 2 + 0];
    int4 i1 = paths[(size_t)p * 2 + 1];
    int idxs[8] = {i0.x, i0.y, i0.z, i0.w, i1.x, i1.y, i1.z, i1.w};

    float acc = 0.0f;
#pragma unroll
    for (int l = 0; l < 8; ++l) {
        int idx = idxs[l];
        if (idx >= 0) {                   // mask: -1 entries contribute 0
            const float4* row = ea + (size_t)idx * 4;
            float4 a0 = row[0], a1 = row[1], a2 = row[2], a3 = row[3];
            float4 v0 = sev[l * 4 + 0], v1 = sev[l * 4 + 1];
            float4 v2 = sev[l * 4 + 2], v3 = sev[l * 4 + 3];
            acc += a0.x * v0.x + a0.y * v0.y + a0.z * v0.z + a0.w * v0.w;
            acc += a1.x * v1.x + a1.y * v1.y + a1.z * v1.z + a1.w * v1.w;
            acc += a2.x * v2.x + a2.y * v2.y + a2.z * v2.z + a2.w * v2.w;
            acc += a3.x * v3.x + a3.y * v3.y + a3.z * v3.z + a3.w * v3.w;
        }
    }
    acc *= 0.125f;                        // mean over full L=8

    out[key] = acc;                       // single winner per key: race-free
}

extern "C" void kernel_launch(void* const* d_in, const int* in_sizes, int n_in,
                              void* d_out, int out_size, void* d_ws, size_t ws_size,
                              hipStream_t stream) {
    // inputs: 0=num_nodes(int,1) 1=edge_attr(f32,E*16) 2=src(int,P) 3=dst(int,P)
    //         4=paths(int,P*8) 5=edge_vector(f32,8*16)
    const float* edge_attr = (const float*)d_in[1];
    const int*   src       = (const int*)d_in[2];
    const int*   dst       = (const int*)d_in[3];
    const int*   paths     = (const int*)d_in[4];
    const float* ev        = (const float*)d_in[5];

    int P = in_sizes[2];
    unsigned N = (unsigned)llround(sqrt((double)out_size));   // 8192

    float*    out  = (float*)d_out;
    unsigned* keys = (unsigned*)d_ws;                          // TS u32 = 8 MB
    unsigned* vals = keys + TS;                                // TS u32 = 8 MB

    hipMemsetAsync(d_out, 0, (size_t)out_size * sizeof(float), stream);
    hipMemsetAsync(d_ws, 0, (size_t)TS * 2u * sizeof(unsigned), stream);

    const int B = 256;
    const int G = (P + B - 1) / B;
    k_insert<<<G, B, 0, stream>>>(src, dst, keys, vals, P, N);
    k_compute<<<G, B, 0, stream>>>((const float4*)edge_attr, (const int4*)paths,
                                   (const float4*)ev, src, dst, keys, vals, out, P, N);
}

// Round 3
// 470.100 us; speedup vs baseline: 1.1954x; 1.1954x over previous
//
#include <hip/hip_runtime.h>
#include <math.h>

// Last-write-wins scatter, 2 scattered passes over the output matrix:
//   Pass 1: out (zeroed, viewed as u32) <- atomicMax(slot, p+1). Highest
//           pair index per slot = last writer (numpy set semantics).
//   Pass 2 (fused): thread p reads out[slot]; if == p+1 it is the unique
//           winner -> compute dot and overwrite slot with float bits.
//           Losers reading after the winner's store see float bits, which
//           can never equal loser_p+1 (would need |acc| < 2^-105; exact 0.0
//           gives bits 0x0, not in [1,P]). Race-free in practice.

__global__ void k_elect(const int* __restrict__ src, const int* __restrict__ dst,
                        unsigned* __restrict__ out, int P, unsigned N) {
    int p = blockIdx.x * blockDim.x + threadIdx.x;
    if (p >= P) return;
    size_t slot = (size_t)(unsigned)src[p] * N + (unsigned)dst[p];
    atomicMax(&out[slot], (unsigned)(p + 1));
}

__global__ void k_fused(const float4* __restrict__ ea, const int4* __restrict__ paths,
                        const float4* __restrict__ ev, const int* __restrict__ src,
                        const int* __restrict__ dst, float* __restrict__ out,
                        int P, unsigned N) {
    __shared__ float4 sev[32];            // edge_vector: 8 x 16 fp32 = 32 float4
    int t = threadIdx.x;
    if (t < 32) sev[t] = ev[t];
    __syncthreads();
    int p = blockIdx.x * blockDim.x + t;
    if (p >= P) return;

    size_t slot = (size_t)(unsigned)src[p] * N + (unsigned)dst[p];
    unsigned wid = ((const unsigned*)out)[slot];      // scattered read (LLC-warm)
    if (wid != (unsigned)(p + 1)) return;             // ~0.75% of threads exit

    int4 i0 = paths[(size_t)p * 2 + 0];
    int4 i1 = paths[(size_t)p * 2 + 1];
    int idxs[8] = {i0.x, i0.y, i0.z, i0.w, i1.x, i1.y, i1.z, i1.w};

    float acc = 0.0f;
#pragma unroll
    for (int l = 0; l < 8; ++l) {
        int idx = idxs[l];
        if (idx >= 0) {                   // mask: -1 entries contribute 0
            const float4* row = ea + (size_t)idx * 4;
            float4 a0 = row[0], a1 = row[1], a2 = row[2], a3 = row[3];
            float4 v0 = sev[l * 4 + 0], v1 = sev[l * 4 + 1];
            float4 v2 = sev[l * 4 + 2], v3 = sev[l * 4 + 3];
            acc += a0.x * v0.x + a0.y * v0.y + a0.z * v0.z + a0.w * v0.w;
            acc += a1.x * v1.x + a1.y * v1.y + a1.z * v1.z + a1.w * v1.w;
            acc += a2.x * v2.x + a2.y * v2.y + a2.z * v2.z + a2.w * v2.w;
            acc += a3.x * v3.x + a3.y * v3.y + a3.z * v3.z + a3.w * v3.w;
        }
    }
    acc *= 0.125f;                        // mean over full L=8 (matches torch/jax)

    out[slot] = acc;                      // unique winner: race-free overwrite
}

extern "C" void kernel_launch(void* const* d_in, const int* in_sizes, int n_in,
                              void* d_out, int out_size, void* d_ws, size_t ws_size,
                              hipStream_t stream) {
    // inputs: 0=num_nodes(int,1) 1=edge_attr(f32,E*16) 2=src(int,P) 3=dst(int,P)
    //         4=paths(int,P*8) 5=edge_vector(f32,8*16)
    const float* edge_attr = (const float*)d_in[1];
    const int*   src       = (const int*)d_in[2];
    const int*   dst       = (const int*)d_in[3];
    const int*   paths     = (const int*)d_in[4];
    const float* ev        = (const float*)d_in[5];

    int P = in_sizes[2];
    unsigned N = (unsigned)llround(sqrt((double)out_size));   // 8192

    hipMemsetAsync(d_out, 0, (size_t)out_size * sizeof(float), stream);

    const int B = 256;
    const int G = (P + B - 1) / B;
    k_elect<<<G, B, 0, stream>>>(src, dst, (unsigned*)d_out, P, N);
    k_fused<<<G, B, 0, stream>>>((const float4*)edge_attr, (const int4*)paths,
                                 (const float4*)ev, src, dst, (float*)d_out, P, N);
}